// Round 1
// baseline (329.562 us; speedup 1.0000x reference)
//
#include <hip/hip_runtime.h>
#include <hip/hip_bf16.h>
#include <math.h>

// Problem constants (match reference setup_inputs)
#define NN 50000      // nodes
#define NE 800000     // edges
#define DD 128        // feature dim (D_IN == H1 == H2 == H3)
#define NG 500        // graphs
#define NC 16         // classes

// ---------------- histogram ----------------
__global__ void hist_kernel(const int* __restrict__ keys, int* __restrict__ counts, int n) {
    int i = blockIdx.x * blockDim.x + threadIdx.x;
    if (i < n) atomicAdd(&counts[keys[i]], 1);
}

// ---------------- block-wise exclusive scan (1024/block) ----------------
__global__ __launch_bounds__(1024) void scan_block_kernel(const int* __restrict__ in,
                                                          int* __restrict__ outEx,
                                                          int* __restrict__ bsum, int n) {
    __shared__ int s[1024];
    int t = threadIdx.x;
    int i = blockIdx.x * 1024 + t;
    int v = (i < n) ? in[i] : 0;
    s[t] = v;
    __syncthreads();
    for (int d = 1; d < 1024; d <<= 1) {
        int xv = (t >= d) ? s[t - d] : 0;
        __syncthreads();
        s[t] += xv;
        __syncthreads();
    }
    if (i < n) outEx[i] = s[t] - v;
    if (t == 1023) bsum[blockIdx.x] = s[t];
}

// single-block exclusive scan for n <= 1024; optionally writes total
__global__ __launch_bounds__(1024) void scan_one_block_kernel(const int* __restrict__ in,
                                                              int* __restrict__ outEx,
                                                              int n, int* __restrict__ totalDst) {
    __shared__ int s[1024];
    int t = threadIdx.x;
    int v = (t < n) ? in[t] : 0;
    s[t] = v;
    __syncthreads();
    for (int d = 1; d < 1024; d <<= 1) {
        int xv = (t >= d) ? s[t - d] : 0;
        __syncthreads();
        s[t] += xv;
        __syncthreads();
    }
    if (t < n) outEx[t] = s[t] - v;
    if (t == 1023 && totalDst) *totalDst = s[1023];
}

__global__ __launch_bounds__(1024) void add_offsets_kernel(int* __restrict__ offs,
                                                           const int* __restrict__ boff, int n) {
    int i = blockIdx.x * 1024 + threadIdx.x;
    if (i < n) offs[i] += boff[blockIdx.x];
}

// ---------------- CSR fill (group edge srcs by dst) ----------------
__global__ void fill_csr_kernel(const int* __restrict__ esrc, const int* __restrict__ edst,
                                const int* __restrict__ offs, int* __restrict__ cursor,
                                int* __restrict__ csr, int nE) {
    int i = blockIdx.x * blockDim.x + threadIdx.x;
    if (i < nE) {
        int d = edst[i];
        int p = offs[d] + atomicAdd(&cursor[d], 1);
        csr[p] = esrc[i];
    }
}

// ---------------- GEMM: Y[M,128] = X[M,128] @ W[128,128] ----------------
// BM=64, BN=64, K=128 (single K tile). A^T in LDS (pitch 68), B in LDS.
__global__ __launch_bounds__(256) void gemm128_kernel(const float* __restrict__ X,
                                                      const float* __restrict__ W,
                                                      float* __restrict__ Y, int M) {
    __shared__ float At[128][68];  // At[k][r], pitch 68 floats (16B-aligned rows)
    __shared__ float Bs[128][64];  // Bs[k][c]

    const int m0 = blockIdx.x * 64;
    const int n0 = blockIdx.y * 64;
    const int tid = threadIdx.x;

    // Load A tile: 64 rows x 128 cols, transposed into LDS.
    #pragma unroll
    for (int i = 0; i < 8; ++i) {
        int slot = tid + i * 256;            // 2048 float4 slots
        int r = slot >> 5;                   // 0..63
        int c4 = (slot & 31) << 2;           // 0..124
        int row = m0 + r;
        float4 v = make_float4(0.f, 0.f, 0.f, 0.f);
        if (row < M) v = *reinterpret_cast<const float4*>(&X[row * 128 + c4]);
        At[c4 + 0][r] = v.x;
        At[c4 + 1][r] = v.y;
        At[c4 + 2][r] = v.z;
        At[c4 + 3][r] = v.w;
    }
    // Load B tile: 128 k x 64 cols.
    #pragma unroll
    for (int i = 0; i < 8; ++i) {
        int slot = tid + i * 256;            // 2048 float4 slots
        int k = slot >> 4;                   // 0..127
        int c4 = (slot & 15) << 2;           // 0..60
        *reinterpret_cast<float4*>(&Bs[k][c4]) =
            *reinterpret_cast<const float4*>(&W[k * 128 + n0 + c4]);
    }
    __syncthreads();

    const int tx = tid & 15;
    const int ty = tid >> 4;
    float acc[4][4] = {};

    #pragma unroll 8
    for (int k = 0; k < 128; ++k) {
        float4 av = *reinterpret_cast<const float4*>(&At[k][ty << 2]);
        float4 bv = *reinterpret_cast<const float4*>(&Bs[k][tx << 2]);
        float a[4] = {av.x, av.y, av.z, av.w};
        float b[4] = {bv.x, bv.y, bv.z, bv.w};
        #pragma unroll
        for (int i = 0; i < 4; ++i)
            #pragma unroll
            for (int j = 0; j < 4; ++j)
                acc[i][j] = fmaf(a[i], b[j], acc[i][j]);
    }

    #pragma unroll
    for (int i = 0; i < 4; ++i) {
        int row = m0 + (ty << 2) + i;
        if (row < M) {
            float4 v = make_float4(acc[i][0], acc[i][1], acc[i][2], acc[i][3]);
            *reinterpret_cast<float4*>(&Y[row * 128 + n0 + (tx << 2)]) = v;
        }
    }
}

// ---------------- propagate (pull via CSR): out = in + sum_{e: dst=i} in[src] ----------------
// one wave per node; lane holds float2 (128 floats = 64 lanes x 2)
__global__ __launch_bounds__(256) void prop_kernel(const float* __restrict__ In,
                                                   const int* __restrict__ offs,
                                                   const int* __restrict__ csr,
                                                   const float* __restrict__ bias,
                                                   float* __restrict__ Out,
                                                   int n, int reluFlag) {
    int wave = (blockIdx.x * blockDim.x + threadIdx.x) >> 6;
    int lane = threadIdx.x & 63;
    if (wave >= n) return;
    const float2* In2 = reinterpret_cast<const float2*>(In);
    float2 acc = In2[wave * 64 + lane];
    int e = offs[wave], e1 = offs[wave + 1];
    // unroll-by-2 for a bit of MLP
    for (; e + 1 < e1; e += 2) {
        int s0 = csr[e], s1 = csr[e + 1];
        float2 v0 = In2[s0 * 64 + lane];
        float2 v1 = In2[s1 * 64 + lane];
        acc.x += v0.x + v1.x;
        acc.y += v0.y + v1.y;
    }
    if (e < e1) {
        int s0 = csr[e];
        float2 v0 = In2[s0 * 64 + lane];
        acc.x += v0.x;
        acc.y += v0.y;
    }
    if (reluFlag) {
        float2 b = reinterpret_cast<const float2*>(bias)[lane];
        acc.x = fmaxf(acc.x + b.x, 0.f);
        acc.y = fmaxf(acc.y + b.y, 0.f);
    }
    reinterpret_cast<float2*>(Out)[wave * 64 + lane] = acc;
}

// ---------------- segmented pooling over sorted idx ranges ----------------
__global__ __launch_bounds__(256) void pool_kernel(const float* __restrict__ P2,
                                                   const int* __restrict__ gstart,
                                                   float* __restrict__ pooled) {
    int g = blockIdx.x;
    int t = threadIdx.x;       // 256
    int f = t & 127;           // feature
    int h = t >> 7;            // half (0/1)
    int s = gstart[g], e = gstart[g + 1];
    float acc = 0.f;
    for (int i = s + h; i < e; i += 2) acc += P2[i * 128 + f];
    __shared__ float red[256];
    red[t] = acc;
    __syncthreads();
    if (t < 128) pooled[g * 128 + t] = red[t] + red[t + 128];
}

// ---------------- head: pooled@W2 + cnt*b2 -> relu(@W3+b3) -> @W4+b4 -> log_softmax ----------------
__global__ __launch_bounds__(128) void head_kernel(const float* __restrict__ pooled,
                                                   const int* __restrict__ cnt,
                                                   const float* __restrict__ W2, const float* __restrict__ b2,
                                                   const float* __restrict__ W3, const float* __restrict__ b3,
                                                   const float* __restrict__ W4, const float* __restrict__ b4,
                                                   float* __restrict__ out) {
    int g = blockIdx.x, t = threadIdx.x;   // 128 threads
    __shared__ float vs[128], hs[128], zs[128], os[16];
    vs[t] = pooled[g * 128 + t];
    __syncthreads();
    float c = (float)cnt[g];
    float a = c * b2[t];
    #pragma unroll 8
    for (int k = 0; k < 128; ++k) a = fmaf(vs[k], W2[k * 128 + t], a);
    hs[t] = a;
    __syncthreads();
    float z = b3[t];
    #pragma unroll 8
    for (int k = 0; k < 128; ++k) z = fmaf(hs[k], W3[k * 128 + t], z);
    zs[t] = fmaxf(z, 0.f);
    __syncthreads();
    if (t < 16) {
        float oo = b4[t];
        #pragma unroll 8
        for (int k = 0; k < 128; ++k) oo = fmaf(zs[k], W4[k * 16 + t], oo);
        os[t] = oo;
    }
    __syncthreads();
    if (t < 16) {
        float m = -INFINITY;
        #pragma unroll
        for (int k = 0; k < 16; ++k) m = fmaxf(m, os[k]);
        float ssum = 0.f;
        #pragma unroll
        for (int k = 0; k < 16; ++k) ssum += expf(os[k] - m);
        out[g * 16 + t] = os[t] - m - logf(ssum);
    }
}

extern "C" void kernel_launch(void* const* d_in, const int* in_sizes, int n_in,
                              void* d_out, int out_size, void* d_ws, size_t ws_size,
                              hipStream_t stream) {
    const float* x    = (const float*)d_in[0];
    const int*   esrc = (const int*)d_in[1];
    const int*   edst = (const int*)d_in[2];
    const int*   idx  = (const int*)d_in[3];
    const float* W1   = (const float*)d_in[4];
    const float* b1   = (const float*)d_in[5];
    const float* W2   = (const float*)d_in[6];
    const float* b2   = (const float*)d_in[7];
    const float* W3   = (const float*)d_in[8];
    const float* b3   = (const float*)d_in[9];
    const float* W4   = (const float*)d_in[10];
    const float* b4   = (const float*)d_in[11];
    float* out = (float*)d_out;

    // workspace partition (256B aligned)
    char* w = (char*)d_ws;
    auto alloc = [&](size_t bytes) -> void* {
        void* p = (void*)w;
        w += (bytes + 255) & ~(size_t)255;
        return p;
    };
    int* counts  = (int*)alloc((size_t)NN * 4);       // in-degree
    int* cursor  = (int*)alloc((size_t)NN * 4);       // csr fill cursors
    int* cnt     = (int*)alloc((size_t)NG * 4);       // nodes per graph
    int* offsets = (int*)alloc((size_t)(NN + 1) * 4); // csr row offsets
    int* gstart  = (int*)alloc((size_t)(NG + 1) * 4); // graph segment starts
    int* bsum    = (int*)alloc(64 * 4);
    int* boff    = (int*)alloc(64 * 4);
    int* csr     = (int*)alloc((size_t)NE * 4);       // srcs grouped by dst
    float* y     = (float*)alloc((size_t)NN * DD * 4); // x@W1, later reused as P2
    float* z1    = (float*)alloc((size_t)NN * DD * 4);
    float* pooled= (float*)alloc((size_t)NG * DD * 4);

    // zero counts+cursor+cnt (contiguous region)
    size_t zeroBytes = (size_t)((char*)cnt - (char*)counts) + ((size_t)NG * 4);
    hipMemsetAsync(counts, 0, zeroBytes, stream);

    // 1. histograms
    hist_kernel<<<(NE + 255) / 256, 256, 0, stream>>>(edst, counts, NE);
    hist_kernel<<<(NN + 255) / 256, 256, 0, stream>>>(idx, cnt, NN);

    // 2. exclusive scan of counts -> offsets (49 blocks of 1024 cover 50176 >= NN)
    const int NB = (NN + 1023) / 1024;   // 49
    scan_block_kernel<<<NB, 1024, 0, stream>>>(counts, offsets, bsum, NN);
    scan_one_block_kernel<<<1, 1024, 0, stream>>>(bsum, boff, NB, &offsets[NN]);
    add_offsets_kernel<<<NB, 1024, 0, stream>>>(offsets, boff, NN);

    // 3. graph segment starts from cnt
    scan_one_block_kernel<<<1, 1024, 0, stream>>>(cnt, gstart, NG, &gstart[NG]);

    // 4. fill CSR
    fill_csr_kernel<<<(NE + 255) / 256, 256, 0, stream>>>(esrc, edst, offsets, cursor, csr, NE);

    // 5. y = x @ W1
    dim3 ggrid((NN + 63) / 64, 2);
    gemm128_kernel<<<ggrid, 256, 0, stream>>>(x, W1, y, NN);

    // 6. z1 = relu(propagate(y) + b1)
    prop_kernel<<<NN / 4, 256, 0, stream>>>(y, offsets, csr, b1, z1, NN, 1);

    // 7. P2 = propagate(z1) (reuse y)
    prop_kernel<<<NN / 4, 256, 0, stream>>>(z1, offsets, csr, nullptr, y, NN, 0);

    // 8. pooled_pre[g] = sum of P2 rows in graph g
    pool_kernel<<<NG, 256, 0, stream>>>(y, gstart, pooled);

    // 9. head
    head_kernel<<<NG, 128, 0, stream>>>(pooled, cnt, W2, b2, W3, b3, W4, b4, out);
}

// Round 3
// 321.548 us; speedup vs baseline: 1.0249x; 1.0249x over previous
//
#include <hip/hip_runtime.h>
#include <hip/hip_bf16.h>
#include <math.h>

// Problem constants (match reference setup_inputs)
#define NN 50000      // nodes
#define NE 800000     // edges
#define DD 128        // feature dim
#define NG 500        // graphs
#define NC 16         // classes

using short8 = __attribute__((ext_vector_type(8))) short;
using f32x4  = __attribute__((ext_vector_type(4))) float;

// fp32 -> bf16 (RNE) raw bits
static __device__ __forceinline__ ushort f2bf(float f) {
    __hip_bfloat16 h = __float2bfloat16(f);
    ushort r;
    __builtin_memcpy(&r, &h, sizeof(r));
    return r;
}
// packed pair of bf16 (as uint) -> two floats
static __device__ __forceinline__ float bflo(uint v) { return __uint_as_float(v << 16); }
static __device__ __forceinline__ float bfhi(uint v) { return __uint_as_float(v & 0xffff0000u); }

// ---------------- histogram (in-degree) ----------------
__global__ void hist_kernel(const int* __restrict__ keys, int* __restrict__ counts, int n) {
    int i = blockIdx.x * blockDim.x + threadIdx.x;
    if (i < n) atomicAdd(&counts[keys[i]], 1);
}

// ---------------- block-wise exclusive scan (1024/block) ----------------
__global__ __launch_bounds__(1024) void scan_block_kernel(const int* __restrict__ in,
                                                          int* __restrict__ outEx,
                                                          int* __restrict__ bsum, int n) {
    __shared__ int s[1024];
    int t = threadIdx.x;
    int i = blockIdx.x * 1024 + t;
    int v = (i < n) ? in[i] : 0;
    s[t] = v;
    __syncthreads();
    for (int d = 1; d < 1024; d <<= 1) {
        int xv = (t >= d) ? s[t - d] : 0;
        __syncthreads();
        s[t] += xv;
        __syncthreads();
    }
    if (i < n) outEx[i] = s[t] - v;
    if (t == 1023) bsum[blockIdx.x] = s[t];
}

__global__ __launch_bounds__(1024) void scan_one_block_kernel(const int* __restrict__ in,
                                                              int* __restrict__ outEx,
                                                              int n, int* __restrict__ totalDst) {
    __shared__ int s[1024];
    int t = threadIdx.x;
    int v = (t < n) ? in[t] : 0;
    s[t] = v;
    __syncthreads();
    for (int d = 1; d < 1024; d <<= 1) {
        int xv = (t >= d) ? s[t - d] : 0;
        __syncthreads();
        s[t] += xv;
        __syncthreads();
    }
    if (t < n) outEx[t] = s[t] - v;
    if (t == 1023 && totalDst) *totalDst = s[1023];
}

__global__ __launch_bounds__(1024) void add_offsets_kernel(int* __restrict__ offs,
                                                           const int* __restrict__ boff, int n) {
    int i = blockIdx.x * 1024 + threadIdx.x;
    if (i < n) offs[i] += boff[blockIdx.x];
}

// ---------------- graph segment starts: binary search on sorted idx ----------------
__global__ void gstart_kernel(const int* __restrict__ idx, int* __restrict__ gstart) {
    int g = blockIdx.x * blockDim.x + threadIdx.x;
    if (g > NG) return;
    if (g == NG) { gstart[NG] = NN; return; }
    int lo = 0, hi = NN;
    while (lo < hi) {
        int mid = (lo + hi) >> 1;
        if (idx[mid] < g) lo = mid + 1; else hi = mid;
    }
    gstart[g] = lo;
}

// ---------------- CSR fill (group edge srcs by dst) ----------------
__global__ void fill_csr_kernel(const int* __restrict__ esrc, const int* __restrict__ edst,
                                const int* __restrict__ offs, int* __restrict__ cursor,
                                int* __restrict__ csr, int nE) {
    int i = blockIdx.x * blockDim.x + threadIdx.x;
    if (i < nE) {
        int d = edst[i];
        int p = offs[d] + atomicAdd(&cursor[d], 1);
        csr[p] = esrc[i];
    }
}

// ---------------- W1^T bf16 conversion (tiny) ----------------
__global__ void convert_w1t_kernel(const float* __restrict__ W1, ushort* __restrict__ W1t) {
    int flat = blockIdx.x * 256 + threadIdx.x;   // 0..16383 over [k][n]
    if (flat < 128 * 128) {
        int k = flat >> 7, n = flat & 127;
        W1t[n * 128 + k] = f2bf(W1[flat]);
    }
}

// ---------------- MFMA GEMM: Y_bf16[M,128] = bf16(X_f32[M,128]) @ W1t^T ----------------
// BM=128, BN=128 (full), 4 waves in 2x2, each wave 64x64. No LDS: A from global
// fp32 (converted in-reg), B from pre-transposed bf16 W1t (L2-hot, 32 KB).
__global__ __launch_bounds__(256) void gemm_mfma_kernel(const float* __restrict__ X,
                                                        const ushort* __restrict__ W1t,
                                                        ushort* __restrict__ Y, int M) {
    const int tid = threadIdx.x;
    const int wave = tid >> 6, lane = tid & 63;
    const int wm = wave >> 1, wn = wave & 1;
    const int m0 = blockIdx.x * 128 + wm * 64;
    const int n0 = wn * 64;
    const int lr = lane & 15;          // row (A) / col (B,D) within 16
    const int lk = (lane >> 4) * 8;    // k-offset within 32

    int rows[4];
    bool valid[4];
    #pragma unroll
    for (int m = 0; m < 4; ++m) {
        rows[m] = m0 + m * 16 + lr;
        valid[m] = rows[m] < M;
    }

    f32x4 acc[4][4] = {};  // [m][n]

    #pragma unroll
    for (int kc = 0; kc < 4; ++kc) {
        const int kb = kc * 32 + lk;
        short8 a[4];
        #pragma unroll
        for (int m = 0; m < 4; ++m) {
            union { short8 v; ushort u[8]; } ua;
            if (valid[m]) {
                const float* p = &X[(size_t)rows[m] * 128 + kb];
                float4 v0 = *reinterpret_cast<const float4*>(p);
                float4 v1 = *reinterpret_cast<const float4*>(p + 4);
                ua.u[0] = f2bf(v0.x); ua.u[1] = f2bf(v0.y);
                ua.u[2] = f2bf(v0.z); ua.u[3] = f2bf(v0.w);
                ua.u[4] = f2bf(v1.x); ua.u[5] = f2bf(v1.y);
                ua.u[6] = f2bf(v1.z); ua.u[7] = f2bf(v1.w);
            } else {
                #pragma unroll
                for (int j = 0; j < 8; ++j) ua.u[j] = 0;
            }
            a[m] = ua.v;
        }
        short8 b[4];
        #pragma unroll
        for (int n = 0; n < 4; ++n) {
            b[n] = *reinterpret_cast<const short8*>(&W1t[(size_t)(n0 + n * 16 + lr) * 128 + kb]);
        }
        #pragma unroll
        for (int m = 0; m < 4; ++m)
            #pragma unroll
            for (int n = 0; n < 4; ++n)
                acc[m][n] = __builtin_amdgcn_mfma_f32_16x16x32_bf16(a[m], b[n], acc[m][n], 0, 0, 0);
    }

    // store: D lane mapping col=lane&15, row=(lane>>4)*4+r
    const int rbase = (lane >> 4) * 4;
    #pragma unroll
    for (int m = 0; m < 4; ++m) {
        #pragma unroll
        for (int r = 0; r < 4; ++r) {
            int row = m0 + m * 16 + rbase + r;
            if (row < M) {
                #pragma unroll
                for (int n = 0; n < 4; ++n) {
                    Y[(size_t)row * 128 + n0 + n * 16 + lr] = f2bf(acc[m][n][r]);
                }
            }
        }
    }
}

// ---------------- prop1: z1 = relu(y + sum_in y[src] + b1), bf16 in/out ----------------
// one wave per node; lane holds packed bf16x2 (4B); rows are 256B coalesced
__global__ __launch_bounds__(256) void prop1_kernel(const ushort* __restrict__ Yb,
                                                    const int* __restrict__ offs,
                                                    const int* __restrict__ csr,
                                                    const float* __restrict__ b1,
                                                    ushort* __restrict__ Z1, int n) {
    int node = (blockIdx.x * blockDim.x + threadIdx.x) >> 6;
    int lane = threadIdx.x & 63;
    if (node >= n) return;
    const uint* Y32 = reinterpret_cast<const uint*>(Yb);
    uint v = Y32[(size_t)node * 64 + lane];
    float ax = bflo(v), ay = bfhi(v);
    int e = offs[node], e1 = offs[node + 1];
    for (; e + 4 <= e1; e += 4) {
        int s0 = csr[e], s1 = csr[e + 1], s2 = csr[e + 2], s3 = csr[e + 3];
        uint v0 = Y32[(size_t)s0 * 64 + lane];
        uint v1 = Y32[(size_t)s1 * 64 + lane];
        uint v2 = Y32[(size_t)s2 * 64 + lane];
        uint v3 = Y32[(size_t)s3 * 64 + lane];
        ax += bflo(v0) + bflo(v1) + bflo(v2) + bflo(v3);
        ay += bfhi(v0) + bfhi(v1) + bfhi(v2) + bfhi(v3);
    }
    for (; e < e1; ++e) {
        uint v0 = Y32[(size_t)csr[e] * 64 + lane];
        ax += bflo(v0);
        ay += bfhi(v0);
    }
    float2 b = reinterpret_cast<const float2*>(b1)[lane];
    ax = fmaxf(ax + b.x, 0.f);
    ay = fmaxf(ay + b.y, 0.f);
    uint outv = ((uint)f2bf(ay) << 16) | (uint)f2bf(ax);
    reinterpret_cast<uint*>(Z1)[(size_t)node * 64 + lane] = outv;
}

// ---------------- fused prop2 + pool ----------------
// pooled[g] = sum_{i in g} z1[i] + sum_{p in [offs[gstart[g]], offs[gstart[g+1]])} z1[csr[p]]
// grid = 2 blocks per graph; partial sums atomically added to zeroed pooled.
__global__ __launch_bounds__(256) void prop2pool_kernel(const ushort* __restrict__ Z1,
                                                        const int* __restrict__ offs,
                                                        const int* __restrict__ csr,
                                                        const int* __restrict__ gstart,
                                                        float* __restrict__ pooled) {
    int g = blockIdx.x >> 1;
    int half = blockIdx.x & 1;
    int w = threadIdx.x >> 6, lane = threadIdx.x & 63;
    int lw = half * 4 + w;   // 0..7 across the two blocks of this graph
    int gs = gstart[g], ge = gstart[g + 1];
    const uint* Z32 = reinterpret_cast<const uint*>(Z1);
    float ax = 0.f, ay = 0.f;
    // node part: waves stride the graph's node range
    for (int i = gs + lw; i < ge; i += 8) {
        uint v = Z32[(size_t)i * 64 + lane];
        ax += bflo(v); ay += bfhi(v);
    }
    // edge part (edges of graph g are contiguous in csr): each wave owns
    // 4-wide slots strided by 32; per-element guard (each p in exactly one slot)
    int ps = offs[gs], pe = offs[ge];
    for (int p0 = ps + lw * 4; p0 < pe; p0 += 32) {
        #pragma unroll
        for (int j = 0; j < 4; ++j) {
            int p = p0 + j;
            if (p < pe) {
                uint v = Z32[(size_t)csr[p] * 64 + lane];
                ax += bflo(v); ay += bfhi(v);
            }
        }
    }
    __shared__ float red[4][128];
    red[w][lane * 2] = ax;
    red[w][lane * 2 + 1] = ay;
    __syncthreads();
    if (threadIdx.x < 128) {
        float s = red[0][threadIdx.x] + red[1][threadIdx.x] + red[2][threadIdx.x] + red[3][threadIdx.x];
        atomicAdd(&pooled[g * 128 + threadIdx.x], s);
    }
}

// ---------------- head ----------------
__global__ __launch_bounds__(128) void head_kernel(const float* __restrict__ pooled,
                                                   const int* __restrict__ gstart,
                                                   const float* __restrict__ W2, const float* __restrict__ b2,
                                                   const float* __restrict__ W3, const float* __restrict__ b3,
                                                   const float* __restrict__ W4, const float* __restrict__ b4,
                                                   float* __restrict__ out) {
    int g = blockIdx.x, t = threadIdx.x;   // 128 threads
    __shared__ float vs[128], hs[128], zs[128], os[16];
    vs[t] = pooled[g * 128 + t];
    __syncthreads();
    float c = (float)(gstart[g + 1] - gstart[g]);
    float a = c * b2[t];
    #pragma unroll 8
    for (int k = 0; k < 128; ++k) a = fmaf(vs[k], W2[k * 128 + t], a);
    hs[t] = a;
    __syncthreads();
    float z = b3[t];
    #pragma unroll 8
    for (int k = 0; k < 128; ++k) z = fmaf(hs[k], W3[k * 128 + t], z);
    zs[t] = fmaxf(z, 0.f);
    __syncthreads();
    if (t < 16) {
        float oo = b4[t];
        #pragma unroll 8
        for (int k = 0; k < 128; ++k) oo = fmaf(zs[k], W4[k * 16 + t], oo);
        os[t] = oo;
    }
    __syncthreads();
    if (t < 16) {
        float m = -INFINITY;
        #pragma unroll
        for (int k = 0; k < 16; ++k) m = fmaxf(m, os[k]);
        float ssum = 0.f;
        #pragma unroll
        for (int k = 0; k < 16; ++k) ssum += expf(os[k] - m);
        out[g * 16 + t] = os[t] - m - logf(ssum);
    }
}

extern "C" void kernel_launch(void* const* d_in, const int* in_sizes, int n_in,
                              void* d_out, int out_size, void* d_ws, size_t ws_size,
                              hipStream_t stream) {
    const float* x    = (const float*)d_in[0];
    const int*   esrc = (const int*)d_in[1];
    const int*   edst = (const int*)d_in[2];
    const int*   idx  = (const int*)d_in[3];
    const float* W1   = (const float*)d_in[4];
    const float* b1   = (const float*)d_in[5];
    const float* W2   = (const float*)d_in[6];
    const float* b2   = (const float*)d_in[7];
    const float* W3   = (const float*)d_in[8];
    const float* b3   = (const float*)d_in[9];
    const float* W4   = (const float*)d_in[10];
    const float* b4   = (const float*)d_in[11];
    float* out = (float*)d_out;

    // workspace partition (256B aligned)
    char* w = (char*)d_ws;
    auto alloc = [&](size_t bytes) -> void* {
        void* p = (void*)w;
        w += (bytes + 255) & ~(size_t)255;
        return p;
    };
    int* counts  = (int*)alloc((size_t)NN * 4);        // in-degree
    int* cursor  = (int*)alloc((size_t)NN * 4);        // csr fill cursors
    int* offsets = (int*)alloc((size_t)(NN + 1) * 4);  // csr row offsets
    int* gstart  = (int*)alloc((size_t)(NG + 1) * 4);  // graph segment starts
    int* bsum    = (int*)alloc(64 * 4);
    int* boff    = (int*)alloc(64 * 4);
    int* csr     = (int*)alloc((size_t)NE * 4);        // srcs grouped by dst
    ushort* w1t  = (ushort*)alloc((size_t)DD * DD * 2);// W1^T bf16
    ushort* y    = (ushort*)alloc((size_t)NN * DD * 2);// bf16(x@W1)
    ushort* z1   = (ushort*)alloc((size_t)NN * DD * 2);// bf16 hidden
    float* pooled= (float*)alloc((size_t)NG * DD * 4);

    // zero counts+cursor FULLY (including alignment padding) and pooled
    size_t zeroBytes = (size_t)((char*)offsets - (char*)counts);
    hipMemsetAsync(counts, 0, zeroBytes, stream);
    hipMemsetAsync(pooled, 0, (size_t)NG * DD * 4, stream);

    // in-degree histogram
    hist_kernel<<<(NE + 255) / 256, 256, 0, stream>>>(edst, counts, NE);

    // exclusive scan of counts -> offsets
    const int NB = (NN + 1023) / 1024;   // 49
    scan_block_kernel<<<NB, 1024, 0, stream>>>(counts, offsets, bsum, NN);
    scan_one_block_kernel<<<1, 1024, 0, stream>>>(bsum, boff, NB, &offsets[NN]);
    add_offsets_kernel<<<NB, 1024, 0, stream>>>(offsets, boff, NN);

    // graph segment starts (binary search on sorted idx)
    gstart_kernel<<<2, 256, 0, stream>>>(idx, gstart);

    // fill CSR
    fill_csr_kernel<<<(NE + 255) / 256, 256, 0, stream>>>(esrc, edst, offsets, cursor, csr, NE);

    // W1^T bf16
    convert_w1t_kernel<<<64, 256, 0, stream>>>(W1, w1t);

    // y = bf16(x @ W1)
    gemm_mfma_kernel<<<(NN + 127) / 128, 256, 0, stream>>>(x, w1t, y, NN);

    // z1 = relu(propagate(y) + b1)  (bf16 -> bf16)
    prop1_kernel<<<NN / 4, 256, 0, stream>>>(y, offsets, csr, b1, z1, NN);

    // pooled[g] = node-sum + edge-gather-sum (fused propagate+pool)
    prop2pool_kernel<<<NG * 2, 256, 0, stream>>>(z1, offsets, csr, gstart, pooled);

    // head
    head_kernel<<<NG, 128, 0, stream>>>(pooled, gstart, W2, b2, W3, b3, W4, b4, out);
}